// Round 1
// baseline (322.163 us; speedup 1.0000x reference)
//
#include <hip/hip_runtime.h>
#include <hip/hip_bf16.h>

#define DM   1024
#define SEQ  2048
#define NH   16
#define DH   64
#define BH   64        // B * NH
#define MTOT 8192      // B * SEQ

typedef __attribute__((ext_vector_type(8))) short  short8;
typedef __attribute__((ext_vector_type(4))) short  short4v;
typedef __attribute__((ext_vector_type(4))) float  f32x4;
typedef __attribute__((ext_vector_type(4))) float  fvec4;
typedef unsigned short ushort_t;

#define AS1 __attribute__((address_space(1)))
#define AS3 __attribute__((address_space(3)))

static __device__ __forceinline__ unsigned short f2bf(float f){
  __bf16 h = (__bf16)f;
  return __builtin_bit_cast(unsigned short, h);
}

static __device__ __forceinline__ float fexp2(float x){
  float r;
  asm("v_exp_f32 %0, %1\n\ts_nop 0" : "=v"(r) : "v"(x));
  return r;
}

static __device__ __forceinline__ void gld16(const void* g, void* l){
  __builtin_amdgcn_global_load_lds((const AS1 int*)g, (AS3 int*)l, 16, 0, 0);
}

// ---------------- cast x (fp32 -> bf16), 8 elems/thread ----------------
__global__ void k_cast_x(const float* __restrict__ x, ushort_t* __restrict__ xb){
  const size_t i = (size_t)blockIdx.x*256 + threadIdx.x;   // 1048576 threads
  const fvec4* xv = (const fvec4*)x;
  fvec4 a = xv[2*i], b = xv[2*i+1];
  short8 r;
  #pragma unroll
  for (int j=0;j<4;++j) r[j]   = (short)f2bf(a[j]);
  #pragma unroll
  for (int j=0;j<4;++j) r[4+j] = (short)f2bf(b[j]);
  ((short8*)xb)[i] = r;
}

// -------- cast + transpose weights: W[k][n] fp32 -> Wt[n][k] bf16 --------
__global__ void k_cast_wt(const float* __restrict__ wq, const float* __restrict__ wk,
                          const float* __restrict__ wv, const float* __restrict__ wo,
                          ushort_t* __restrict__ wt){
  const int z = blockIdx.y;
  const float* W = (z==0)?wq:(z==1)?wk:(z==2)?wv:wo;
  ushort_t* Wt = wt + (size_t)z*DM*DM;
  const int k0 = (blockIdx.x & 15)*64, n0 = (blockIdx.x >> 4)*64;
  __shared__ float tile[64][65];
  const int t = threadIdx.x;
  #pragma unroll
  for (int it=0; it<4; ++it){
    int c = it*256 + t;
    int rr = c>>4, cc = c&15;
    fvec4 v = *(const fvec4*)(W + (size_t)(k0+rr)*DM + n0 + cc*4);
    #pragma unroll
    for (int j=0;j<4;++j) tile[cc*4+j][rr] = v[j];
  }
  __syncthreads();
  #pragma unroll
  for (int it=0; it<4; ++it){
    int c = it*256 + t;
    int nn = c>>4, kk = c&15;
    short4v r;
    #pragma unroll
    for (int j=0;j<4;++j) r[j] = (short)f2bf(tile[nn][kk*4+j]);
    *(short4v*)(Wt + (size_t)(n0+nn)*DM + k0 + kk*4) = r;
  }
}

// ---------------- 128x128 GEMM, m97 structure ----------------
// MODE 0: C = A@W + b -> bf16 with [b,h,s,d] head-split remap (QKV)
// MODE 1: C = A@W + b -> fp32 linear (output projection)
template<int MODE>
__global__ __launch_bounds__(256, 2)
void k_gemm128(const ushort_t* __restrict__ A, const ushort_t* __restrict__ WtBase,
               const float* __restrict__ b0, const float* __restrict__ b1,
               const float* __restrict__ b2,
               ushort_t* __restrict__ obf, float* __restrict__ of32){
  const int z = blockIdx.z;
  const ushort_t* Wt = WtBase + (size_t)z*DM*DM;
  const float* bias = (z==0)? b0 : (z==1? b1 : b2);
  __shared__ ushort_t Al[128*32];
  __shared__ ushort_t Bl[128*32];
  const int t = threadIdx.x;
  const int wid = t>>6, l = t&63, g = l>>4, li = l&15;
  const int m0 = blockIdx.x*128, n0 = blockIdx.y*128;
  const int wr = (wid>>1)*64, wc = (wid&1)*64;
  const int srow = t>>2, schunk = (t&3)*8;

  f32x4 acc[4][4] = {};

  for (int kt = 0; kt < DM; kt += 32){
    __syncthreads();
    #pragma unroll
    for (int c = 0; c < 2; ++c){
      gld16(A  + (size_t)(m0 + c*64 + srow)*DM + kt + schunk, (char*)Al + c*4096 + wid*1024);
      gld16(Wt + (size_t)(n0 + c*64 + srow)*DM + kt + schunk, (char*)Bl + c*4096 + wid*1024);
    }
    __syncthreads();
    short8 af[4], bw[4];
    #pragma unroll
    for (int mt=0; mt<4; ++mt)
      af[mt] = *(const short8*)(Al + (wr + mt*16 + li)*32 + g*8);
    #pragma unroll
    for (int nt=0; nt<4; ++nt)
      bw[nt] = *(const short8*)(Bl + (wc + nt*16 + li)*32 + g*8);
    #pragma unroll
    for (int mt=0; mt<4; ++mt)
      #pragma unroll
      for (int nt=0; nt<4; ++nt)
        acc[mt][nt] = __builtin_amdgcn_mfma_f32_16x16x32_bf16(af[mt], bw[nt], acc[mt][nt], 0,0,0);
  }

  #pragma unroll
  for (int nt=0; nt<4; ++nt){
    const int n = n0 + wc + nt*16 + li;
    const float bn = bias[n];
    #pragma unroll
    for (int mt=0; mt<4; ++mt){
      #pragma unroll
      for (int r=0; r<4; ++r){
        const int m = m0 + wr + mt*16 + g*4 + r;
        const float v = acc[mt][nt][r] + bn;
        if constexpr (MODE==0){
          const int bb = m >> 11, s = m & 2047, h = n >> 6, d = n & 63;
          obf[(size_t)z*MTOT*DM + (((size_t)(bb*NH + h)*SEQ + s)*DH + d)] = f2bf(v);
        } else {
          of32[(size_t)m*DM + n] = v;
        }
      }
    }
  }
}

// ------- V[bh][s][d] -> Vt[bh][d][s] (LDS tile transpose) -------
__global__ void k_transpose_v(const ushort_t* __restrict__ V, ushort_t* __restrict__ Vt){
  const int bh = blockIdx.y, s0 = blockIdx.x*64;
  __shared__ ushort_t tile[64][72];
  const int t = threadIdx.x;
  const ushort_t* Vh = V + (size_t)bh*SEQ*DH;
  ushort_t* Vth = Vt + (size_t)bh*DH*SEQ;
  #pragma unroll
  for (int it=0; it<2; ++it){
    int c = it*256 + t;
    int s_ = c>>3, d8 = (c&7)*8;
    short8 v = *(const short8*)(Vh + (size_t)(s0+s_)*DH + d8);
    #pragma unroll
    for (int j=0;j<8;++j) tile[d8+j][s_] = (ushort_t)v[j];
  }
  __syncthreads();
  #pragma unroll
  for (int it=0; it<2; ++it){
    int c = it*256 + t;
    int d_ = c>>3, s8 = (c&7)*8;
    short8 r = *(const short8*)(&tile[d_][s8]);
    *(short8*)(Vth + (size_t)d_*SEQ + s0 + s8) = r;
  }
}

// ---------------- flash attention ----------------
// 4 waves/block, QBLK=128 (32 q/wave), KVBLK=64.  S^T = K·Q^T (swapped
// operands -> row reduce is 2 shfl_xor), P via per-wave swizzled LDS,
// ctx = P·V with V pre-transposed per head.
#define CEXP 0.18033688011112042f   // log2(e)/sqrt(DH)

__global__ __launch_bounds__(256, 2)
void k_attn(const ushort_t* __restrict__ Qb, const ushort_t* __restrict__ Kb,
            const ushort_t* __restrict__ Vtb, ushort_t* __restrict__ ctx){
  const int bh = blockIdx.y, b = bh>>4, h = bh&15;
  const int t = threadIdx.x, wid = t>>6, l = t&63, g = l>>4, li = l&15;
  const int q0 = blockIdx.x*128;
  __shared__ ushort_t Kl[64*64];
  __shared__ ushort_t Vl[64*64];
  __shared__ ushort_t Pl[4][32*64];
  const ushort_t* Qh = Qb  + (size_t)bh*SEQ*DH;
  const ushort_t* Kh = Kb  + (size_t)bh*SEQ*DH;
  const ushort_t* Vh = Vtb + (size_t)bh*DH*SEQ;
  char* Plb = (char*)&Pl[wid][0];
  char* Klb = (char*)Kl;
  char* Vlb = (char*)Vl;

  short8 qf[2][2];
  #pragma unroll
  for (int nt=0; nt<2; ++nt)
    #pragma unroll
    for (int ks=0; ks<2; ++ks)
      qf[nt][ks] = *(const short8*)(Qh + (size_t)(q0 + wid*32 + nt*16 + li)*DH + ks*32 + g*8);

  f32x4 o[2][4] = {};
  float m_[2] = {-1e30f, -1e30f};
  float lsum[2] = {0.f, 0.f};

  for (int kv0 = 0; kv0 < SEQ; kv0 += 64){
    __syncthreads();
    // stage K tile [64 kv][64 d] and Vt tile [64 d][64 s], both XOR-swizzled
    #pragma unroll
    for (int it=0; it<2; ++it){
      int c = it*256 + t;
      int row = c>>3, ch = c&7;
      short8 kv_ = *(const short8*)(Kh + (size_t)(kv0+row)*DH + ch*8);
      *(short8*)(Klb + row*128 + ((ch ^ (row&7))<<4)) = kv_;
      short8 vv  = *(const short8*)(Vh + (size_t)row*SEQ + kv0 + ch*8);
      *(short8*)(Vlb + row*128 + ((ch ^ (row&7))<<4)) = vv;
    }
    __syncthreads();

    // S^T = K · Q^T   (D-frag: kv = 4g+r + 16*mt, q = li + 16*nt)
    f32x4 s_[2][4] = {};
    #pragma unroll
    for (int ks=0; ks<2; ++ks){
      short8 af[4];
      #pragma unroll
      for (int mt=0; mt<4; ++mt){
        int row = mt*16 + li;
        af[mt] = *(const short8*)(Klb + row*128 + (((ks*4+g) ^ (row&7))<<4));
      }
      #pragma unroll
      for (int nt=0; nt<2; ++nt)
        #pragma unroll
        for (int mt=0; mt<4; ++mt)
          s_[nt][mt] = __builtin_amdgcn_mfma_f32_16x16x32_bf16(af[mt], qf[nt][ks], s_[nt][mt], 0,0,0);
    }

    // online softmax (per lane state for q = 16*nt + li)
    float fac[2];
    #pragma unroll
    for (int nt=0; nt<2; ++nt){
      float tm = -1e30f;
      #pragma unroll
      for (int mt=0; mt<4; ++mt)
        #pragma unroll
        for (int r=0; r<4; ++r) tm = fmaxf(tm, s_[nt][mt][r]);
      tm = fmaxf(tm, __shfl_xor(tm, 16));
      tm = fmaxf(tm, __shfl_xor(tm, 32));
      const float mn = fmaxf(m_[nt], tm);
      fac[nt] = fexp2((m_[nt] - mn)*CEXP);
      m_[nt] = mn;
      float rs = 0.f;
      const int q = nt*16 + li;
      #pragma unroll
      for (int mt=0; mt<4; ++mt){
        short4v pk;
        #pragma unroll
        for (int r=0; r<4; ++r){
          float p = fexp2((s_[nt][mt][r] - mn)*CEXP);
          rs += p;
          pk[r] = (short)f2bf(p);
        }
        *(short4v*)(Plb + ((q*128 + (mt*16 + g*4)*2) ^ ((q&7)<<4))) = pk;
      }
      rs += __shfl_xor(rs, 16);
      rs += __shfl_xor(rs, 32);
      lsum[nt] = lsum[nt]*fac[nt] + rs;
    }

    // rescale running O (O rows are q = 16*qt + 4g + r -> fetch factor by shfl)
    #pragma unroll
    for (int qt=0; qt<2; ++qt)
      #pragma unroll
      for (int r=0; r<4; ++r){
        float fr = __shfl(fac[qt], g*4 + r);
        #pragma unroll
        for (int dt=0; dt<4; ++dt) o[qt][dt][r] *= fr;
      }

    // ctx += P · V
    #pragma unroll
    for (int ks=0; ks<2; ++ks){
      short8 pa[2];
      #pragma unroll
      for (int qt=0; qt<2; ++qt){
        int q = qt*16 + li;
        pa[qt] = *(const short8*)(Plb + ((q*128 + ks*64 + g*16) ^ ((q&7)<<4)));
      }
      short8 vb[4];
      #pragma unroll
      for (int dt=0; dt<4; ++dt){
        int d = dt*16 + li;
        vb[dt] = *(const short8*)(Vlb + d*128 + (((ks*4+g) ^ (d&7))<<4));
      }
      #pragma unroll
      for (int qt=0; qt<2; ++qt)
        #pragma unroll
        for (int dt=0; dt<4; ++dt)
          o[qt][dt] = __builtin_amdgcn_mfma_f32_16x16x32_bf16(pa[qt], vb[dt], o[qt][dt], 0,0,0);
    }
  }

  // epilogue: ctx[b, q, h*64+d] = O / lsum
  #pragma unroll
  for (int qt=0; qt<2; ++qt){
    const float inv = 1.f / lsum[qt];
    #pragma unroll
    for (int r=0; r<4; ++r){
      const float w = __shfl(inv, g*4 + r);
      const int qrow = q0 + wid*32 + qt*16 + g*4 + r;
      #pragma unroll
      for (int dt=0; dt<4; ++dt)
        ctx[((size_t)(b*SEQ + qrow))*DM + h*DH + dt*16 + li] = f2bf(o[qt][dt][r] * w);
    }
  }
}

extern "C" void kernel_launch(void* const* d_in, const int* in_sizes, int n_in,
                              void* d_out, int out_size, void* d_ws, size_t ws_size,
                              hipStream_t stream){
  const float* x  = (const float*)d_in[0];
  const float* wq = (const float*)d_in[1];
  const float* bq = (const float*)d_in[2];
  const float* wk = (const float*)d_in[3];
  const float* bk = (const float*)d_in[4];
  const float* wv = (const float*)d_in[5];
  const float* bv = (const float*)d_in[6];
  const float* wo = (const float*)d_in[7];
  const float* bo = (const float*)d_in[8];
  float* out = (float*)d_out;

  // workspace layout (bf16/ushort elems): 104 MiB total
  ushort_t* xb  = (ushort_t*)d_ws;                 // [8192][1024]
  ushort_t* wt  = xb  + (size_t)MTOT*DM;           // 4x [1024][1024] transposed
  ushort_t* qkv = wt  + (size_t)4*DM*DM;           // Q,K,V each [bh][s][d]
  ushort_t* vt  = qkv + (size_t)3*MTOT*DM;         // [bh][d][s]
  ushort_t* ctx = vt  + (size_t)MTOT*DM;           // [8192][1024]

  k_cast_x<<<4096, 256, 0, stream>>>(x, xb);
  k_cast_wt<<<dim3(256,4), 256, 0, stream>>>(wq, wk, wv, wo, wt);
  k_gemm128<0><<<dim3(64,8,3), 256, 0, stream>>>(xb, wt, bq, bk, bv, qkv, nullptr);
  k_transpose_v<<<dim3(32,64), 256, 0, stream>>>(qkv + (size_t)2*MTOT*DM, vt);
  k_attn<<<dim3(16,64), 256, 0, stream>>>(qkv, qkv + (size_t)MTOT*DM, vt, ctx);
  k_gemm128<1><<<dim3(64,8,1), 256, 0, stream>>>(ctx, wt + (size_t)3*DM*DM, bo, bo, bo, nullptr, out);
}

// Round 2
// 283.962 us; speedup vs baseline: 1.1345x; 1.1345x over previous
//
#include <hip/hip_runtime.h>
#include <hip/hip_bf16.h>

#define DM   1024
#define SEQ  2048
#define NH   16
#define DH   64
#define BH   64        // B * NH
#define MTOT 8192      // B * SEQ

typedef __attribute__((ext_vector_type(8)))  short short8;
typedef __attribute__((ext_vector_type(4)))  short short4v;
typedef __attribute__((ext_vector_type(4)))  float f32x4;
typedef __attribute__((ext_vector_type(16))) float f32x16;
typedef __attribute__((ext_vector_type(4)))  float fvec4;
typedef __attribute__((ext_vector_type(4)))  int   i32x4;
typedef unsigned short ushort_t;

#define AS1 __attribute__((address_space(1)))
#define AS3 __attribute__((address_space(3)))

// log2(e)/sqrt(DH) folded into Q at projection time
#define QSCALE 0.18033688011112042f
// defer-max threshold: 8 nats = 11.54 in log2 domain
#define THR_L2 11.541560327111707f

static __device__ __forceinline__ unsigned short f2bf(float f){
  __bf16 h = (__bf16)f;
  return __builtin_bit_cast(unsigned short, h);
}

static __device__ __forceinline__ float fexp2(float x){
  float r;
  asm("v_exp_f32 %0, %1\n\ts_nop 0" : "=v"(r) : "v"(x));
  return r;
}

static __device__ __forceinline__ void gld16(const void* g, void* l){
  __builtin_amdgcn_global_load_lds((const AS1 int*)g, (AS3 int*)l, 16, 0, 0);
}

// ---------------- cast x (fp32 -> bf16), 8 elems/thread ----------------
__global__ void k_cast_x(const float* __restrict__ x, ushort_t* __restrict__ xb){
  const size_t i = (size_t)blockIdx.x*256 + threadIdx.x;
  const fvec4* xv = (const fvec4*)x;
  fvec4 a = xv[2*i], b = xv[2*i+1];
  short8 r;
  #pragma unroll
  for (int j=0;j<4;++j) r[j]   = (short)f2bf(a[j]);
  #pragma unroll
  for (int j=0;j<4;++j) r[4+j] = (short)f2bf(b[j]);
  ((short8*)xb)[i] = r;
}

// -------- cast + transpose weights: W[k][n] fp32 -> Wt[n][k] bf16 --------
__global__ void k_cast_wt(const float* __restrict__ wq, const float* __restrict__ wk,
                          const float* __restrict__ wv, const float* __restrict__ wo,
                          ushort_t* __restrict__ wt){
  const int z = blockIdx.y;
  const float* W = (z==0)?wq:(z==1)?wk:(z==2)?wv:wo;
  ushort_t* Wt = wt + (size_t)z*DM*DM;
  const int k0 = (blockIdx.x & 15)*64, n0 = (blockIdx.x >> 4)*64;
  __shared__ float tile[64][65];
  const int t = threadIdx.x;
  #pragma unroll
  for (int it=0; it<4; ++it){
    int c = it*256 + t;
    int rr = c>>4, cc = c&15;
    fvec4 v = *(const fvec4*)(W + (size_t)(k0+rr)*DM + n0 + cc*4);
    #pragma unroll
    for (int j=0;j<4;++j) tile[cc*4+j][rr] = v[j];
  }
  __syncthreads();
  #pragma unroll
  for (int it=0; it<4; ++it){
    int c = it*256 + t;
    int nn = c>>4, kk = c&15;
    short4v r;
    #pragma unroll
    for (int j=0;j<4;++j) r[j] = (short)f2bf(tile[nn][kk*4+j]);
    *(short4v*)(Wt + (size_t)(n0+nn)*DM + k0 + kk*4) = r;
  }
}

// ---------------- 128x128 GEMM, m97 structure ----------------
// MODE 0: C = A@W + b (QKV). z==0: *QSCALE, bf16 [bh][s][d]. z==1: bf16 [bh][s][d].
//         z==2: bf16 TRANSPOSED [bh][d][s] (V ready for attention B-operand).
// MODE 1: C = A@W + b -> fp32 linear (output projection)
template<int MODE>
__global__ __launch_bounds__(256, 2)
void k_gemm128(const ushort_t* __restrict__ A, const ushort_t* __restrict__ WtBase,
               const float* __restrict__ b0, const float* __restrict__ b1,
               const float* __restrict__ b2,
               ushort_t* __restrict__ obf, float* __restrict__ of32){
  const int z = blockIdx.z;
  const ushort_t* Wt = WtBase + (size_t)z*DM*DM;
  const float* bias = (z==0)? b0 : (z==1? b1 : b2);
  __shared__ ushort_t Al[128*32];
  __shared__ ushort_t Bl[128*32];
  const int t = threadIdx.x;
  const int wid = t>>6, l = t&63, g = l>>4, li = l&15;
  const int m0 = blockIdx.x*128, n0 = blockIdx.y*128;
  const int wr = (wid>>1)*64, wc = (wid&1)*64;
  const int srow = t>>2, schunk = (t&3)*8;

  f32x4 acc[4][4] = {};

  for (int kt = 0; kt < DM; kt += 32){
    __syncthreads();
    #pragma unroll
    for (int c = 0; c < 2; ++c){
      gld16(A  + (size_t)(m0 + c*64 + srow)*DM + kt + schunk, (char*)Al + c*4096 + wid*1024);
      gld16(Wt + (size_t)(n0 + c*64 + srow)*DM + kt + schunk, (char*)Bl + c*4096 + wid*1024);
    }
    __syncthreads();
    short8 af[4], bw[4];
    #pragma unroll
    for (int mt=0; mt<4; ++mt)
      af[mt] = *(const short8*)(Al + (wr + mt*16 + li)*32 + g*8);
    #pragma unroll
    for (int nt=0; nt<4; ++nt)
      bw[nt] = *(const short8*)(Bl + (wc + nt*16 + li)*32 + g*8);
    #pragma unroll
    for (int mt=0; mt<4; ++mt)
      #pragma unroll
      for (int nt=0; nt<4; ++nt)
        acc[mt][nt] = __builtin_amdgcn_mfma_f32_16x16x32_bf16(af[mt], bw[nt], acc[mt][nt], 0,0,0);
  }

  if constexpr (MODE==0){
    if (z == 2){
      // V: write transposed [bh][d][s]
      ushort_t* vt = obf + (size_t)2*MTOT*DM;
      #pragma unroll
      for (int nt=0; nt<4; ++nt){
        const int n = n0 + wc + nt*16 + li;
        const float bn = bias[n];
        const int h = n>>6, d = n&63;
        #pragma unroll
        for (int mt=0; mt<4; ++mt){
          const int m = m0 + wr + mt*16 + g*4;
          const int bb = m >> 11, s = m & 2047;
          short4v pk;
          #pragma unroll
          for (int r=0; r<4; ++r) pk[r] = (short)f2bf(acc[mt][nt][r] + bn);
          *(short4v*)(vt + (((size_t)(bb*NH + h)*DH + d)*SEQ + s)) = pk;
        }
      }
    } else {
      const float sc = (z==0) ? QSCALE : 1.f;
      #pragma unroll
      for (int nt=0; nt<4; ++nt){
        const int n = n0 + wc + nt*16 + li;
        const float bn = bias[n];
        #pragma unroll
        for (int mt=0; mt<4; ++mt){
          #pragma unroll
          for (int r=0; r<4; ++r){
            const int m = m0 + wr + mt*16 + g*4 + r;
            const float v = (acc[mt][nt][r] + bn)*sc;
            const int bb = m >> 11, s = m & 2047, h = n >> 6, d = n & 63;
            obf[(size_t)z*MTOT*DM + (((size_t)(bb*NH + h)*SEQ + s)*DH + d)] = f2bf(v);
          }
        }
      }
    }
  } else {
    #pragma unroll
    for (int nt=0; nt<4; ++nt){
      const int n = n0 + wc + nt*16 + li;
      const float bn = bias[n];
      #pragma unroll
      for (int mt=0; mt<4; ++mt){
        #pragma unroll
        for (int r=0; r<4; ++r){
          const int m = m0 + wr + mt*16 + g*4 + r;
          of32[(size_t)m*DM + n] = acc[mt][nt][r] + bn;
        }
      }
    }
  }
}

// ---------------- flash attention, 32x32 swapped structure ----------------
// 4 waves/block, 32 q-rows/wave (128/block), KVBLK=64.
// S^T = K·Q^T  (D-layout: col=q=lane&31, row=kv=(r&3)+8*(r>>2)+4*hi per 32-blk)
// -> per-lane full P column slice -> in-register softmax (defer-max THR)
// -> cvt_pk_bf16 + permlane32_swap -> PV A-frags, V pre-transposed [d][s].
// K/V in LDS double-buffered via global_load_lds, chunk-XOR swizzled.
__global__ __launch_bounds__(256, 2)
void k_attn(const ushort_t* __restrict__ Qb, const ushort_t* __restrict__ Kb,
            const ushort_t* __restrict__ Vtb, ushort_t* __restrict__ ctx){
  const int bh = blockIdx.y, b = bh>>4, h = bh&15;
  const int t = threadIdx.x, wid = t>>6, lane = t&63;
  const int lq = lane&31, hi = lane>>5;
  const int qw = blockIdx.x*128 + wid*32;
  __shared__ ushort_t Kl[2][64*64];
  __shared__ ushort_t Vl[2][64*64];
  const ushort_t* Qh = Qb  + (size_t)bh*SEQ*DH;
  const ushort_t* Kh = Kb  + (size_t)bh*SEQ*DH;
  const ushort_t* Vh = Vtb + (size_t)bh*DH*SEQ;

  // Q B-frags (already scaled by log2(e)/8): lane holds Q[qw+lq][ks*16+hi*8+j]
  short8 qf[4];
  #pragma unroll
  for (int ks=0; ks<4; ++ks)
    qf[ks] = *(const short8*)(Qh + (size_t)(qw+lq)*DH + ks*16 + hi*8);

  f32x16 o0 = {}, o1 = {};
  float m_ = 0.f, ls = 0.f;

  const int srl = lane>>3, scp = lane&7;
  #define STAGE(kv0, bi) do {                                              \
    _Pragma("unroll")                                                      \
    for (int i8=0; i8<2; ++i8){                                            \
      const int row = wid*16 + i8*8 + srl;                                 \
      const int c = scp ^ (row&7);                                         \
      gld16(Kh + (size_t)((kv0)+row)*DH + c*8,                             \
            (char*)&Kl[bi][0] + (wid*16+i8*8)*128);                        \
      gld16(Vh + (size_t)row*SEQ + (kv0) + c*8,                            \
            (char*)&Vl[bi][0] + (wid*16+i8*8)*128);                        \
    }                                                                      \
  } while(0)

  STAGE(0, 0);
  __syncthreads();

  int cur = 0;
  for (int t64 = 0; t64 < SEQ/64; ++t64){
    if (t64 < SEQ/64 - 1){
      if (cur) STAGE((t64+1)*64, 0); else STAGE((t64+1)*64, 1);
    }
    const char* Kb_ = (const char*)&Kl[cur][0];
    const char* Vb_ = (const char*)&Vl[cur][0];

    // ---- QK^T (swapped): sN holds S^T for kv-block N ----
    short8 kf[8];
    #pragma unroll
    for (int blk=0; blk<2; ++blk){
      const int row = blk*32 + lq;
      #pragma unroll
      for (int ks=0; ks<4; ++ks)
        kf[blk*4+ks] = *(const short8*)(Kb_ + row*128 + (((2*ks+hi) ^ (row&7))<<4));
    }
    f32x16 s0 = {}, s1 = {};
    __builtin_amdgcn_s_setprio(1);
    #pragma unroll
    for (int ks=0; ks<4; ++ks){
      s0 = __builtin_amdgcn_mfma_f32_32x32x16_bf16(kf[ks],   qf[ks], s0, 0,0,0);
      s1 = __builtin_amdgcn_mfma_f32_32x32x16_bf16(kf[4+ks], qf[ks], s1, 0,0,0);
    }
    __builtin_amdgcn_s_setprio(0);

    // ---- online softmax with defer-max ----
    float tm = s0[0];
    #pragma unroll
    for (int r=1; r<16; ++r) tm = fmaxf(tm, s0[r]);
    #pragma unroll
    for (int r=0; r<16; ++r) tm = fmaxf(tm, s1[r]);
    tm = fmaxf(tm, __shfl_xor(tm, 32));

    if (!__all(tm <= m_ + THR_L2)){
      const float mn = fmaxf(m_, tm);
      const float fac = fexp2(m_ - mn);
      m_ = mn; ls *= fac;
      #pragma unroll
      for (int r=0; r<16; ++r){
        const float fr = __shfl(fac, (r&3) + 8*(r>>2) + 4*hi);
        o0[r] *= fr; o1[r] *= fr;
      }
    }
    #pragma unroll
    for (int r=0; r<16; ++r){ float e = fexp2(s0[r]-m_); s0[r]=e; ls+=e; }
    #pragma unroll
    for (int r=0; r<16; ++r){ float e = fexp2(s1[r]-m_); s1[r]=e; ls+=e; }

    // ---- pack P to PV A-frags: cvt_pk + permlane32_swap ----
    short8 pa[4];
    #pragma unroll
    for (int blk=0; blk<2; ++blk){
      #pragma unroll
      for (int half=0; half<2; ++half){
        i32x4 w;
        #pragma unroll
        for (int wp=0; wp<2; ++wp){
          const int base = half*8 + 2*wp;
          float a0 = blk ? s1[base]   : s0[base];
          float a1 = blk ? s1[base+1] : s0[base+1];
          float c0 = blk ? s1[base+4] : s0[base+4];
          float c1 = blk ? s1[base+5] : s0[base+5];
          int x, y;
          asm("v_cvt_pk_bf16_f32 %0, %1, %2" : "=v"(x) : "v"(a0), "v"(a1));
          asm("v_cvt_pk_bf16_f32 %0, %1, %2" : "=v"(y) : "v"(c0), "v"(c1));
          asm("v_permlane32_swap_b32 %0, %1" : "+v"(x), "+v"(y));
          w[wp] = x; w[2+wp] = y;
        }
        pa[blk*2+half] = __builtin_bit_cast(short8, w);
      }
    }

    // ---- PV: ctx += P · V ----
    short8 vb[8];
    #pragma unroll
    for (int dblk=0; dblk<2; ++dblk){
      const int row = dblk*32 + lq;
      #pragma unroll
      for (int ks=0; ks<4; ++ks)
        vb[dblk*4+ks] = *(const short8*)(Vb_ + row*128 + (((2*ks+hi) ^ (row&7))<<4));
    }
    __builtin_amdgcn_s_setprio(1);
    #pragma unroll
    for (int ks=0; ks<4; ++ks){
      o0 = __builtin_amdgcn_mfma_f32_32x32x16_bf16(pa[ks], vb[ks],   o0, 0,0,0);
      o1 = __builtin_amdgcn_mfma_f32_32x32x16_bf16(pa[ks], vb[4+ks], o1, 0,0,0);
    }
    __builtin_amdgcn_s_setprio(0);

    __syncthreads();
    cur ^= 1;
  }

  // ---- epilogue ----
  ls += __shfl_xor(ls, 32);
  const float inv = 1.f / ls;
  #pragma unroll
  for (int r=0; r<16; ++r){
    const float ir = __shfl(inv, (r&3) + 8*(r>>2) + 4*hi);
    const int qrow = qw + (r&3) + 8*(r>>2) + 4*hi;
    ushort_t* dst = ctx + ((size_t)(b*SEQ + qrow))*DM + h*DH;
    dst[lq]    = f2bf(o0[r]*ir);
    dst[32+lq] = f2bf(o1[r]*ir);
  }
  #undef STAGE
}

extern "C" void kernel_launch(void* const* d_in, const int* in_sizes, int n_in,
                              void* d_out, int out_size, void* d_ws, size_t ws_size,
                              hipStream_t stream){
  const float* x  = (const float*)d_in[0];
  const float* wq = (const float*)d_in[1];
  const float* bq = (const float*)d_in[2];
  const float* wk = (const float*)d_in[3];
  const float* bk = (const float*)d_in[4];
  const float* wv = (const float*)d_in[5];
  const float* bv = (const float*)d_in[6];
  const float* wo = (const float*)d_in[7];
  const float* bo = (const float*)d_in[8];
  float* out = (float*)d_out;

  // workspace (ushort elems): xb 16MB | wt 8MB | qkv 48MB (Q,K [bh][s][d]; V [bh][d][s]) | ctx 16MB
  ushort_t* xb  = (ushort_t*)d_ws;
  ushort_t* wt  = xb  + (size_t)MTOT*DM;
  ushort_t* qkv = wt  + (size_t)4*DM*DM;
  ushort_t* ctx = qkv + (size_t)3*MTOT*DM;

  k_cast_x<<<4096, 256, 0, stream>>>(x, xb);
  k_cast_wt<<<dim3(256,4), 256, 0, stream>>>(wq, wk, wv, wo, wt);
  k_gemm128<0><<<dim3(64,8,3), 256, 0, stream>>>(xb, wt, bq, bk, bv, qkv, nullptr);
  k_attn<<<dim3(16,64), 256, 0, stream>>>(qkv, qkv + (size_t)MTOT*DM, qkv + (size_t)2*MTOT*DM, ctx);
  k_gemm128<1><<<dim3(64,8,1), 256, 0, stream>>>(ctx, wt + (size_t)3*DM*DM, bo, bo, bo, nullptr, out);
}